// Round 3
// baseline (630.524 us; speedup 1.0000x reference)
//
#include <hip/hip_runtime.h>

typedef unsigned long long u64;
typedef unsigned int u32;

// Workspace layout:
//   [0, 73728)            : packed weight sign words  swg[o][pos][cw]  (9216 u64)
//   [73728, +3211264)     : packed x sign words pk[n][cw][h][w]  (u64, w-contiguous)
#define PK_OFF 73728
#define NO 8   // output channels per block (register-blocked per thread)
#define WP 4   // pixels (w) per thread

// ---------------------------------------------------------------------------
// Kernel 1: decode codebook weights, pack sign bits.
// wave wid -> (o, pos, cw); lane -> channel i = cw*64+lane.
// ---------------------------------------------------------------------------
__global__ __launch_bounds__(256) void pack_w_kernel(const int* __restrict__ enc,
                                                     const float* __restrict__ cb,
                                                     u64* __restrict__ swg) {
    int wid  = blockIdx.x * 4 + (threadIdx.x >> 6);   // 0..9215
    int lane = threadIdx.x & 63;
    int o   = wid / 36;
    int r   = wid - o * 36;
    int pos = r >> 2;
    int cw  = r & 3;
    int i   = (cw << 6) | lane;
    int f   = o * 2304 + i * 9 + pos;
    int j   = f / 12;
    int t   = f - j * 12;
    float val = cb[enc[j] * 12 + t];
    u64 bits = __ballot(val < 0.0f);
    if (lane == 0) swg[wid] = bits;
}

// ---------------------------------------------------------------------------
// Kernel 2: binarize x. Block=(n,h); wave cw covers channels [cw*64,+64).
// lane = w (56 active). Each lane builds its own word over a coalesced
// c-loop (224B contiguous per load instruction). No ballot, no gather.
// Output: pk[n][cw][h][w], w-contiguous.
// ---------------------------------------------------------------------------
__global__ __launch_bounds__(256) void pack_x_kernel(const float* __restrict__ x,
                                                     u64* __restrict__ pk) {
    int nh   = blockIdx.x;            // n*56 + h
    int cw   = threadIdx.x >> 6;
    int lane = threadIdx.x & 63;
    int n    = nh / 56;
    int h    = nh - n * 56;
    int lw   = lane < 56 ? lane : 55;   // clamp to stay in-bounds
    const float* xp = x + ((size_t)(n * 256 + cw * 64)) * 3136 + h * 56 + lw;
    u32 wlo = 0, whi = 0;
#pragma unroll
    for (int c = 0; c < 32; ++c) {
        float v = xp[(size_t)c * 3136];
        wlo |= (v < 0.0f) ? (1u << c) : 0u;
    }
#pragma unroll
    for (int c = 0; c < 32; ++c) {
        float v = xp[(size_t)(c + 32) * 3136];
        whi |= (v < 0.0f) ? (1u << c) : 0u;
    }
    if (lane < 56)
        pk[(((size_t)n * 4 + cw) * 56 + h) * 56 + lane] = ((u64)whi << 32) | wlo;
}

// ---------------------------------------------------------------------------
// Kernel 3: popcount conv, 4 pixels x 8 output channels per thread.
// s = 256*nr*nc - 2*(Q - corr); Q = sum popc(win ^ sw) with invalid window
// words zeroed; corr (border lanes only) = sum popc(sw) over invalid words.
// ---------------------------------------------------------------------------
__global__ __launch_bounds__(256) void conv_kernel(const u64* __restrict__ pk,
                                                   const u64* __restrict__ swg,
                                                   float* __restrict__ y) {
    __shared__ u64 swl[9 * 8 * 4];   // [pos][j][cw]
    __shared__ int wpl[9 * 8];       // [pos][j] = sum_cw popc(sw)
    int tid = threadIdx.x;
    int o0  = blockIdx.y * NO;
    // 288 entries, 256 threads: grid-stride (R1 bug: `if (tid<288)` left
    // pos==8 entries unwritten -> poison weights for the (2,2) tap).
    for (int idx = tid; idx < 9 * 8 * 4; idx += 256) {
        int pos = idx >> 5, rem = idx & 31, j = rem >> 2, cw = rem & 3;
        swl[idx] = swg[(o0 + j) * 36 + pos * 4 + cw];
    }
    if (tid < 72) {
        int pos = tid >> 3, j = tid & 7;
        const u64* p = swg + (o0 + j) * 36 + pos * 4;
        wpl[tid] = __popcll(p[0]) + __popcll(p[1]) + __popcll(p[2]) + __popcll(p[3]);
    }
    __syncthreads();

    int gs = blockIdx.x * 256 + tid;       // 0..25087 (grid.x = 98, exact)
    int n  = gs / 784;
    int r2 = gs - n * 784;
    int h  = r2 / 14;
    int wg = r2 - h * 14;
    int w0 = wg * 4;

    int Q[WP][NO];
#pragma unroll
    for (int p = 0; p < WP; ++p)
#pragma unroll
        for (int j = 0; j < NO; ++j) Q[p][j] = 0;

    const u64* pkn = pk + (size_t)n * 4 * 3136;

#pragma unroll
    for (int cw = 0; cw < 4; ++cw) {
#pragma unroll
        for (int r = 0; r < 3; ++r) {
            int hh = h - 1 + r;
            int hc = hh < 0 ? 0 : (hh > 55 ? 55 : hh);
            const u64* rowp = pkn + ((size_t)cw * 56 + hc) * 56;
            bool hv = (hh >= 0) && (hh <= 55);
            u64 win[6];
#pragma unroll
            for (int c6 = 0; c6 < 6; ++c6) {
                int cc  = w0 - 1 + c6;
                int ccc = cc < 0 ? 0 : (cc > 55 ? 55 : cc);
                u64 v   = rowp[ccc];
                bool ok = hv && (cc >= 0) && (cc <= 55);
                win[c6] = ok ? v : 0ull;
            }
#pragma unroll
            for (int dw = 0; dw < 3; ++dw) {
#pragma unroll
                for (int j = 0; j < NO; ++j) {
                    u64 wv = swl[((r * 3 + dw) * 8 + j) * 4 + cw];
#pragma unroll
                    for (int p = 0; p < WP; ++p) {
                        Q[p][j] += __popcll(win[p + dw] ^ wv);
                    }
                }
            }
        }
    }

    // Border corrections: subtract popc(sw) of zeroed (invalid) window words.
    if (h == 0 || h == 55 || w0 == 0 || w0 == 52) {
#pragma unroll
        for (int j = 0; j < NO; ++j) {
            int crow = 0;
            if (h == 0)  crow += wpl[0 * 8 + j] + wpl[1 * 8 + j] + wpl[2 * 8 + j];
            if (h == 55) crow += wpl[6 * 8 + j] + wpl[7 * 8 + j] + wpl[8 * 8 + j];
#pragma unroll
            for (int p = 0; p < WP; ++p) {
                int w = w0 + p;
                int c = crow;
                if (w == 0) {
                    if (h > 0)  c += wpl[0 * 8 + j];
                    c += wpl[3 * 8 + j];
                    if (h < 55) c += wpl[6 * 8 + j];
                }
                if (w == 55) {
                    if (h > 0)  c += wpl[2 * 8 + j];
                    c += wpl[5 * 8 + j];
                    if (h < 55) c += wpl[8 * 8 + j];
                }
                Q[p][j] -= c;
            }
        }
    }

    int nr = 3 - (h == 0) - (h == 55);
    int base[WP];
#pragma unroll
    for (int p = 0; p < WP; ++p) {
        int w  = w0 + p;
        int nc = 3 - (w == 0) - (w == 55);
        base[p] = 256 * nr * nc;
    }

    float* yb = y + (size_t)(n * 256 + o0) * 3136 + h * 56 + w0;
#pragma unroll
    for (int j = 0; j < NO; ++j) {
        float4 v;
        v.x = (float)(base[0] - 2 * Q[0][j]);
        v.y = (float)(base[1] - 2 * Q[1][j]);
        v.z = (float)(base[2] - 2 * Q[2][j]);
        v.w = (float)(base[3] - 2 * Q[3][j]);
        *(float4*)(yb + (size_t)j * 3136) = v;
    }
}

extern "C" void kernel_launch(void* const* d_in, const int* in_sizes, int n_in,
                              void* d_out, int out_size, void* d_ws, size_t ws_size,
                              hipStream_t stream) {
    const float* x  = (const float*)d_in[0];
    // d_in[1] (latent weight) is unused in the forward value (STE).
    const float* cb = (const float*)d_in[2];
    const int* enc  = (const int*)d_in[3];
    float* y        = (float*)d_out;

    u64* swg = (u64*)d_ws;
    u64* pk  = (u64*)((char*)d_ws + PK_OFF);

    hipLaunchKernelGGL(pack_w_kernel, dim3(2304), dim3(256), 0, stream, enc, cb, swg);
    hipLaunchKernelGGL(pack_x_kernel, dim3(1792), dim3(256), 0, stream, x, pk);
    hipLaunchKernelGGL(conv_kernel, dim3(98, 32), dim3(256), 0, stream, pk, swg, y);
}